// Round 1
// baseline (106.564 us; speedup 1.0000x reference)
//
#include <hip/hip_runtime.h>
#include <hip/hip_bf16.h>
#include <stdint.h>

// Problem constants
#define NB    32    // batch
#define CIN   128
#define HH    56
#define WW    56
#define COUT  256
#define HP    58    // padded height (H+2)
#define WP    64    // padded width (56+2 -> padded to 64)

// ws layout: xp (bf16, NB*HP*WP*CIN = 15,204,352 elems = 30,408,704 B) then
// wpack (bf16, 9*4*4*256*8 = 294,912 elems = 589,824 B)
#define XP_ELEMS   (NB * HP * WP * CIN)

typedef __attribute__((ext_vector_type(4))) float f32x4;
typedef __attribute__((ext_vector_type(8))) short bf16x8;

__device__ __forceinline__ unsigned short f2bf(float f) {
    union { float f; unsigned u; } v; v.f = f;
    unsigned r = v.u + 0x7FFFu + ((v.u >> 16) & 1u);
    return (unsigned short)(r >> 16);
}

__device__ __forceinline__ void gload16(const void* g, void* l) {
    __builtin_amdgcn_global_load_lds(
        (__attribute__((address_space(1))) void*)(void*)g,
        (__attribute__((address_space(3))) void*)l,
        16, 0, 0);
}

// ---------------------------------------------------------------------------
// Pass A: compose per-output-channel filters, store bf16 in wpack layout
// wpack[pos(9)][cib(4)][kpos(4)][o(256)][kin(8)], ci = cib*32 + kpos*8 + kin
// ---------------------------------------------------------------------------
__global__ __launch_bounds__(256) void build_weight(
    const float* __restrict__ dict, const float* __restrict__ coef,
    const int* __restrict__ idxw, unsigned short* __restrict__ wpack) {
    int o = blockIdx.x;
    int tid = threadIdx.x;

    // Reference dtype is int64; harness doc says integers arrive as int32.
    // Detect: if stored as int64 (little-endian), odd 32-bit words are all 0.
    bool mode64 = (idxw[1] == 0) && (idxw[3] == 0) && (idxw[5] == 0) &&
                  (idxw[7] == 0) && (idxw[9] == 0) && (idxw[11] == 0) &&
                  (idxw[13] == 0) && (idxw[15] == 0);

    float c[8]; int di[8];
#pragma unroll
    for (int s = 0; s < 8; ++s) {
        c[s]  = coef[o * 8 + s];
        di[s] = mode64 ? idxw[(o * 8 + s) * 2] : idxw[o * 8 + s];
    }

    for (int j = tid; j < 9 * 128; j += 256) {
        int pos = j >> 7;          // 0..8
        int ci  = j & 127;
        int kh = pos / 3, kw = pos - kh * 3;
        float v = 0.f;
#pragma unroll
        for (int s = 0; s < 8; ++s)
            v += c[s] * dict[((di[s] * CIN + ci) * 3 + kh) * 3 + kw];
        int cib = ci >> 5, kpos = (ci >> 3) & 3, kin = ci & 7;
        wpack[((((pos * 4 + cib) * 4 + kpos) * COUT + o) << 3) + kin] = f2bf(v);
    }
}

// ---------------------------------------------------------------------------
// Pass B: NCHW fp32 -> zero-padded NHWC bf16
// xp[b][ih(58)][iw(64)][ci(128)]; valid x at ih in [1,56], iw in [1,56]
// ---------------------------------------------------------------------------
__global__ __launch_bounds__(256) void pack_x(
    const float* __restrict__ x, unsigned short* __restrict__ xp) {
    int ih = blockIdx.x;   // 0..57
    int b  = blockIdx.y;
    int tid = threadIdx.x;
    size_t obase = ((size_t)(b * HP + ih)) * WP * CIN;

    if (ih == 0 || ih == HP - 1) {
        for (int e = tid; e < WP * CIN; e += 256) xp[obase + e] = 0;
        return;
    }

    __shared__ float xs[CIN][WW + 1];   // +1 pad: odd stride -> no bank conflicts
    int h = ih - 1;
    for (int e = tid; e < CIN * WW; e += 256) {
        int ci = e / WW, w = e - ci * WW;
        xs[ci][w] = x[(((size_t)b * CIN + ci) * HH + h) * WW + w];
    }
    __syncthreads();
    for (int e = tid; e < WP * CIN; e += 256) {
        int iw = e >> 7, ci = e & 127;
        float v = (iw >= 1 && iw <= WW) ? xs[ci][iw - 1] : 0.f;
        xp[obase + e] = f2bf(v);
    }
}

// ---------------------------------------------------------------------------
// Main: implicit-GEMM conv.  Block = 256 Cout x 2 output rows (one b).
// 512 threads = 8 waves; wave grid 4(M) x 2(N); wave tile 64x64.
// K-loop: outer ci-block (BK=32, B staged once), inner 9 taps (A restaged).
// ---------------------------------------------------------------------------
__global__ __launch_bounds__(512, 2) void conv_mfma(
    const unsigned short* __restrict__ xp,
    const unsigned short* __restrict__ wpack,
    float* __restrict__ out) {
    // B tile: [rr(4)][kpos(4)][iw(64)][kin(8)]  (+pad: taps read iw up to 65)
    __shared__ unsigned short Bl[4 * 4 * 64 * 8 + 64];
    // A tile: [kpos(4)][o(256)][kin(8)]
    __shared__ unsigned short Al[4 * 256 * 8];

    int tid  = threadIdx.x;
    int lane = tid & 63;
    int wid  = tid >> 6;       // 0..7
    int wm   = wid >> 1;       // 0..3  (M: 64*wm)
    int wn   = wid & 1;        // 0..1  (output row within band)
    int band = blockIdx.x;     // 0..27
    int b    = blockIdx.y;     // 0..31
    int oh0  = band * 2;

    const int klane = lane >> 4;   // k-group of this lane (0..3)
    const int fl    = lane & 15;

    f32x4 acc[4][4];
    f32x4 zero = {0.f, 0.f, 0.f, 0.f};
#pragma unroll
    for (int i = 0; i < 4; ++i)
#pragma unroll
        for (int j = 0; j < 4; ++j) acc[i][j] = zero;

    for (int cib = 0; cib < 4; ++cib) {
        // Stage B tile: 16 slices of 1 KB (64 lanes x 16 B); wave w -> slices w, w+8.
        // slice s: rr = s>>2, kpos = s&3; lane <-> iw.
#pragma unroll
        for (int t = 0; t < 2; ++t) {
            int s = wid + t * 8;
            int rr = s >> 2, kpos = s & 3;
            const unsigned short* src =
                xp + (((size_t)(b * HP + oh0 + rr)) * WP + lane) * CIN + cib * 32 + kpos * 8;
            gload16(src, &Bl[s * 512]);
        }
#pragma unroll
        for (int pos = 0; pos < 9; ++pos) {
            const int kh = pos / 3, kw = pos - kh * 3;
            // Stage A tile (16 KB): 16 slices; wave w -> slices w, w+8.
#pragma unroll
            for (int t = 0; t < 2; ++t) {
                int s = wid + t * 8;
                const unsigned short* src =
                    wpack + (size_t)(pos * 4 + cib) * 8192 + s * 512 + lane * 8;
                gload16(src, &Al[s * 512]);
            }
            __syncthreads();   // drains vmcnt -> both tiles visible

            bf16x8 af[4], bfr[4];
#pragma unroll
            for (int mf = 0; mf < 4; ++mf) {
                int o = wm * 64 + mf * 16 + fl;
                af[mf] = *(const bf16x8*)&Al[(klane * 256 + o) * 8];
            }
            int rr = wn + kh;
#pragma unroll
            for (int nf = 0; nf < 4; ++nf) {
                int iw = nf * 16 + fl + kw;   // may reach 65 for junk cols (ow>=56)
                bfr[nf] = *(const bf16x8*)&Bl[((rr * 4 + klane) * 64 + iw) * 8];
            }
#pragma unroll
            for (int mf = 0; mf < 4; ++mf)
#pragma unroll
                for (int nf = 0; nf < 4; ++nf)
                    acc[mf][nf] = __builtin_amdgcn_mfma_f32_16x16x32_bf16(
                        af[mf], bfr[nf], acc[mf][nf], 0, 0, 0);
            __syncthreads();   // compute done before next stage overwrites
        }
    }

    // Epilogue: C/D layout col = lane&15, row = (lane>>4)*4 + reg (m89-verified)
    int oh = oh0 + wn;
#pragma unroll
    for (int nf = 0; nf < 4; ++nf) {
        int ow = nf * 16 + fl;
        if (ow < WW) {
#pragma unroll
            for (int mf = 0; mf < 4; ++mf) {
                int ob = wm * 64 + mf * 16 + (lane >> 4) * 4;
                float* dst = out + (((size_t)b * COUT + ob) * HH + oh) * WW + ow;
#pragma unroll
                for (int r = 0; r < 4; ++r)
                    dst[(size_t)r * HH * WW] = acc[mf][nf][r];
            }
        }
    }
}

extern "C" void kernel_launch(void* const* d_in, const int* in_sizes, int n_in,
                              void* d_out, int out_size, void* d_ws, size_t ws_size,
                              hipStream_t stream) {
    const float* x    = (const float*)d_in[0];
    const float* dict = (const float*)d_in[1];
    const float* coef = (const float*)d_in[2];
    const int*   idxw = (const int*)d_in[3];
    float* out = (float*)d_out;

    unsigned short* xp    = (unsigned short*)d_ws;
    unsigned short* wpack = xp + XP_ELEMS;

    build_weight<<<dim3(COUT), dim3(256), 0, stream>>>(dict, coef, idxw, wpack);
    pack_x<<<dim3(HP, NB), dim3(256), 0, stream>>>(x, xp);
    conv_mfma<<<dim3(HH / 2, NB), dim3(512), 0, stream>>>(xp, wpack, out);
}

// Round 2
// 101.930 us; speedup vs baseline: 1.0455x; 1.0455x over previous
//
#include <hip/hip_runtime.h>
#include <hip/hip_bf16.h>
#include <stdint.h>

// Problem constants
#define NB    32    // batch
#define CIN   128
#define HH    56
#define WW    56
#define COUT  256
#define HP    58    // padded height (H+2)
#define WP    64    // padded width (56+2 -> padded to 64)

// ws layout: xp (bf16, NB*HP*WP*CIN) then wpack (bf16, 9*4*4*256*8)
#define XP_ELEMS   (NB * HP * WP * CIN)

typedef __attribute__((ext_vector_type(4))) float f32x4;
typedef __attribute__((ext_vector_type(8))) short bf16x8;

__device__ __forceinline__ unsigned short f2bf(float f) {
    union { float f; unsigned u; } v; v.f = f;
    unsigned r = v.u + 0x7FFFu + ((v.u >> 16) & 1u);
    return (unsigned short)(r >> 16);
}

__device__ __forceinline__ void gload16(const void* g, void* l) {
    __builtin_amdgcn_global_load_lds(
        (__attribute__((address_space(1))) void*)(void*)g,
        (__attribute__((address_space(3))) void*)l,
        16, 0, 0);
}

// ---------------------------------------------------------------------------
// Pass A: compose per-output-channel filters, store bf16 in wpack layout
// wpack[pos(9)][cib(4)][kpos(4)][o(256)][kin(8)], ci = cib*32 + kpos*8 + kin
// ---------------------------------------------------------------------------
__global__ __launch_bounds__(256) void build_weight(
    const float* __restrict__ dict, const float* __restrict__ coef,
    const int* __restrict__ idxw, unsigned short* __restrict__ wpack) {
    int o = blockIdx.x;
    int tid = threadIdx.x;

    // Reference dtype is int64; detect int64 vs int32 storage.
    bool mode64 = (idxw[1] == 0) && (idxw[3] == 0) && (idxw[5] == 0) &&
                  (idxw[7] == 0) && (idxw[9] == 0) && (idxw[11] == 0) &&
                  (idxw[13] == 0) && (idxw[15] == 0);

    float c[8]; int di[8];
#pragma unroll
    for (int s = 0; s < 8; ++s) {
        c[s]  = coef[o * 8 + s];
        di[s] = mode64 ? idxw[(o * 8 + s) * 2] : idxw[o * 8 + s];
    }

    for (int j = tid; j < 9 * 128; j += 256) {
        int pos = j >> 7;          // 0..8
        int ci  = j & 127;
        int kh = pos / 3, kw = pos - kh * 3;
        float v = 0.f;
#pragma unroll
        for (int s = 0; s < 8; ++s)
            v += c[s] * dict[((di[s] * CIN + ci) * 3 + kh) * 3 + kw];
        int cib = ci >> 5, kpos = (ci >> 3) & 3, kin = ci & 7;
        wpack[((((pos * 4 + cib) * 4 + kpos) * COUT + o) << 3) + kin] = f2bf(v);
    }
}

// ---------------------------------------------------------------------------
// Pass B: NCHW fp32 -> zero-padded NHWC bf16
// xp[b][ih(58)][iw(64)][ci(128)]; valid x at ih in [1,56], iw in [1,56]
// ---------------------------------------------------------------------------
__global__ __launch_bounds__(256) void pack_x(
    const float* __restrict__ x, unsigned short* __restrict__ xp) {
    int ih = blockIdx.x;   // 0..57
    int b  = blockIdx.y;
    int tid = threadIdx.x;
    size_t obase = ((size_t)(b * HP + ih)) * WP * CIN;

    if (ih == 0 || ih == HP - 1) {
        for (int e = tid; e < WP * CIN; e += 256) xp[obase + e] = 0;
        return;
    }

    __shared__ float xs[CIN][WW + 1];   // +1 pad: odd stride -> no bank conflicts
    int h = ih - 1;
    for (int e = tid; e < CIN * WW; e += 256) {
        int ci = e / WW, w = e - ci * WW;
        xs[ci][w] = x[(((size_t)b * CIN + ci) * HH + h) * WW + w];
    }
    __syncthreads();
    for (int e = tid; e < WP * CIN; e += 256) {
        int iw = e >> 7, ci = e & 127;
        float v = (iw >= 1 && iw <= WW) ? xs[ci][iw - 1] : 0.f;
        xp[obase + e] = f2bf(v);
    }
}

// ---------------------------------------------------------------------------
// Main: implicit-GEMM conv.  Block = 256 Cout x 2 output rows (one b).
// 512 threads = 8 waves; wave grid 4(M) x 2(N); wave tile 64x64.
// K-loop: 4 cib x 9 taps, DOUBLE-BUFFERED: next tile's global_load_lds is
// issued at the top of each iteration (into the other buffer), so the
// vmcnt(0) drain inside the single per-iteration __syncthreads() lands
// after ~1200 cycles of MFMA — L2 latency hidden.
// ---------------------------------------------------------------------------
__global__ __launch_bounds__(512, 2) void conv_mfma(
    const unsigned short* __restrict__ xp,
    const unsigned short* __restrict__ wpack,
    float* __restrict__ out) {
    // B tile: [rr(4)][kpos(4)][iw(64)][kin(8)]  (+pad: taps read iw up to 65)
    __shared__ unsigned short Bl[2][4 * 4 * 64 * 8 + 64];
    // A tile: [kpos(4)][o(256)][kin(8)]
    __shared__ unsigned short Al[2][4 * 256 * 8];

    int tid  = threadIdx.x;
    int lane = tid & 63;
    int wid  = tid >> 6;       // 0..7
    int wm   = wid >> 1;       // 0..3  (M: 64*wm)
    int wn   = wid & 1;        // 0..1  (output row within band)
    int band = blockIdx.x;     // 0..27
    int b    = blockIdx.y;     // 0..31
    int oh0  = band * 2;

    const int klane = lane >> 4;   // k-group of this lane (0..3)
    const int fl    = lane & 15;

    f32x4 acc[4][4];
    f32x4 zero = {0.f, 0.f, 0.f, 0.f};
#pragma unroll
    for (int i = 0; i < 4; ++i)
#pragma unroll
        for (int j = 0; j < 4; ++j) acc[i][j] = zero;

    // ---- prologue: stage A(cib0,pos0)->Al[0], B(cib0)->Bl[0] ----
#pragma unroll
    for (int t = 0; t < 2; ++t) {
        int s = wid + t * 8;
        const unsigned short* srcA = wpack + (size_t)s * 512 + lane * 8;
        gload16(srcA, &Al[0][s * 512]);
        int rr = s >> 2, kpos = s & 3;
        const unsigned short* srcB =
            xp + (((size_t)(b * HP + oh0 + rr)) * WP + lane) * CIN + kpos * 8;
        gload16(srcB, &Bl[0][s * 512]);
    }
    __syncthreads();

    int abuf = 0;
#pragma unroll
    for (int cib = 0; cib < 4; ++cib) {
        const int bbuf = cib & 1;
#pragma unroll
        for (int pos = 0; pos < 9; ++pos) {
            const int kh = pos / 3, kw = pos - kh * 3;

            // ---- issue next-tile staging into the OTHER buffers ----
            if (pos < 8) {
#pragma unroll
                for (int t = 0; t < 2; ++t) {
                    int s = wid + t * 8;
                    const unsigned short* srcA =
                        wpack + (size_t)((pos + 1) * 4 + cib) * 8192 + s * 512 + lane * 8;
                    gload16(srcA, &Al[abuf ^ 1][s * 512]);
                }
            } else if (cib < 3) {
#pragma unroll
                for (int t = 0; t < 2; ++t) {
                    int s = wid + t * 8;
                    const unsigned short* srcA =
                        wpack + (size_t)(cib + 1) * 8192 + s * 512 + lane * 8;
                    gload16(srcA, &Al[abuf ^ 1][s * 512]);
                    int rr = s >> 2, kpos = s & 3;
                    const unsigned short* srcB =
                        xp + (((size_t)(b * HP + oh0 + rr)) * WP + lane) * CIN +
                        (cib + 1) * 32 + kpos * 8;
                    gload16(srcB, &Bl[bbuf ^ 1][s * 512]);
                }
            }

            // ---- compute (cib,pos) from Al[abuf], Bl[bbuf] ----
            bf16x8 af[4], bfr[4];
#pragma unroll
            for (int mf = 0; mf < 4; ++mf) {
                int o = wm * 64 + mf * 16 + fl;
                af[mf] = *(const bf16x8*)&Al[abuf][(klane * 256 + o) * 8];
            }
            int rr = wn + kh;
#pragma unroll
            for (int nf = 0; nf < 4; ++nf) {
                int iw = nf * 16 + fl + kw;   // may reach 65 for junk cols
                bfr[nf] = *(const bf16x8*)&Bl[bbuf][((rr * 4 + klane) * 64 + iw) * 8];
            }
#pragma unroll
            for (int mf = 0; mf < 4; ++mf)
#pragma unroll
                for (int nf = 0; nf < 4; ++nf)
                    acc[mf][nf] = __builtin_amdgcn_mfma_f32_16x16x32_bf16(
                        af[mf], bfr[nf], acc[mf][nf], 0, 0, 0);

            __syncthreads();   // drains lgkm (reads done) + vmcnt (next tiles in)
            abuf ^= 1;
        }
    }

    // Epilogue: C/D layout col = lane&15, row = (lane>>4)*4 + reg (m89-verified)
    int oh = oh0 + wn;
#pragma unroll
    for (int nf = 0; nf < 4; ++nf) {
        int ow = nf * 16 + fl;
        if (ow < WW) {
#pragma unroll
            for (int mf = 0; mf < 4; ++mf) {
                int ob = wm * 64 + mf * 16 + (lane >> 4) * 4;
                float* dst = out + (((size_t)b * COUT + ob) * HH + oh) * WW + ow;
#pragma unroll
                for (int r = 0; r < 4; ++r)
                    dst[(size_t)r * HH * WW] = acc[mf][nf][r];
            }
        }
    }
}

extern "C" void kernel_launch(void* const* d_in, const int* in_sizes, int n_in,
                              void* d_out, int out_size, void* d_ws, size_t ws_size,
                              hipStream_t stream) {
    const float* x    = (const float*)d_in[0];
    const float* dict = (const float*)d_in[1];
    const float* coef = (const float*)d_in[2];
    const int*   idxw = (const int*)d_in[3];
    float* out = (float*)d_out;

    unsigned short* xp    = (unsigned short*)d_ws;
    unsigned short* wpack = xp + XP_ELEMS;

    build_weight<<<dim3(COUT), dim3(256), 0, stream>>>(dict, coef, idxw, wpack);
    pack_x<<<dim3(HP, NB), dim3(256), 0, stream>>>(x, xp);
    conv_mfma<<<dim3(HH / 2, NB), dim3(512), 0, stream>>>(xp, wpack, out);
}